// Round 1
// baseline (199.374 us; speedup 1.0000x reference)
//
#include <hip/hip_runtime.h>

#define IN_F 512
#define OUT_F 1024
#define K_ACTIVE 11   // ceil(0.01 * 1024)
#define K_IN 6        // ceil(0.01 * 512)

// Transpose weight [OUT_F][IN_F] -> wT [IN_F][OUT_F] so per-lane j-gathers coalesce.
__global__ void transpose_w_kernel(const float* __restrict__ w, float* __restrict__ wT) {
    int idx = blockIdx.x * blockDim.x + threadIdx.x;
    if (idx >= IN_F * OUT_F) return;
    int i = idx >> 10;          // 0..511
    int j = idx & (OUT_F - 1);  // 0..1023
    wT[idx] = w[j * IN_F + i];
}

// One wave (64 lanes) carries one row through all 11 MP steps.
// Per lane: j = lane + 64*q (q=0..15) over OUT_F, i = lane + 64*p (p=0..7) over IN_F.
template <bool USE_T>
__global__ __launch_bounds__(256) void bmp_kernel(const float* __restrict__ x,
                                                  const float* __restrict__ w,
                                                  const float* __restrict__ wT,
                                                  float* __restrict__ out, int rows) {
    __shared__ unsigned short act[4][IN_F];  // per-wave active-index list of x row
    const int lane = threadIdx.x & 63;
    const int wv = threadIdx.x >> 6;
    const int row = blockIdx.x * 4 + wv;
    if (row >= rows) return;

    // ---- 1. build compacted active list of this row of x ----
    const float* xrow = x + (size_t)row * IN_F;
    int cnt = 0;
#pragma unroll
    for (int c = 0; c < IN_F / 64; ++c) {
        int i = c * 64 + lane;
        bool p = (xrow[i] != 0.0f);
        unsigned long long m = __ballot(p);
        int pre = __popcll(m & ((1ull << lane) - 1ull));
        if (p) act[wv][cnt + pre] = (unsigned short)i;
        cnt += __popcll(m);
    }
    __builtin_amdgcn_wave_barrier();

    // ---- 2. xw2[j] = 2 * sum_{i active} W[j][i], fp64, held in registers ----
    double acc[16];
#pragma unroll
    for (int q = 0; q < 16; ++q) acc[q] = 0.0;
    for (int k = 0; k < cnt; ++k) {
        int i = act[wv][k];
#pragma unroll
        for (int q = 0; q < 16; ++q) {
            int j = lane + 64 * q;
            float wv_ = USE_T ? wT[i * OUT_F + j] : w[j * IN_F + i];
            acc[q] += (double)wv_;
        }
    }
#pragma unroll
    for (int q = 0; q < 16; ++q) acc[q] *= 2.0;

    // v = encoded @ W, grown incrementally (one W row per step)
    double vd[8];
#pragma unroll
    for (int p = 0; p < 8; ++p) vd[p] = 0.0;

    unsigned enc = 0;  // per-lane 16-bit mask over q (encoded positions)
    int xr0 = 0, xr1 = 0, xr2 = 0, xr3 = 0, xr4 = 0, xr5 = 0;  // wave-uniform

    for (int t = 0; t < K_ACTIVE; ++t) {
        // ---- residual + argmax over non-encoded j (lambd suppression == exclusion) ----
        double best = -1e300;
        int bestj = OUT_F;
#pragma unroll
        for (int q = 0; q < 16; ++q) {
            if (enc & (1u << q)) continue;
            int j = lane + 64 * q;
            double r = acc[q];
            if (t > 0) {
                r -= (double)(USE_T ? wT[xr0 * OUT_F + j] : w[j * IN_F + xr0]);
                r -= (double)(USE_T ? wT[xr1 * OUT_F + j] : w[j * IN_F + xr1]);
                r -= (double)(USE_T ? wT[xr2 * OUT_F + j] : w[j * IN_F + xr2]);
                r -= (double)(USE_T ? wT[xr3 * OUT_F + j] : w[j * IN_F + xr3]);
                r -= (double)(USE_T ? wT[xr4 * OUT_F + j] : w[j * IN_F + xr4]);
                r -= (double)(USE_T ? wT[xr5 * OUT_F + j] : w[j * IN_F + xr5]);
            }
            if (r > best || (r == best && j < bestj)) { best = r; bestj = j; }
        }
#pragma unroll
        for (int off = 32; off; off >>= 1) {
            double ov = __shfl_xor(best, off);
            int oj = __shfl_xor(bestj, off);
            if (ov > best || (ov == best && oj < bestj)) { best = ov; bestj = oj; }
        }
        if (lane == (bestj & 63)) enc |= 1u << (bestj >> 6);

        // ---- v += W[bestj][:] (row-major, coalesced) ----
        const float* wrow = w + (size_t)bestj * IN_F;
#pragma unroll
        for (int p = 0; p < 8; ++p) vd[p] += (double)wrow[lane + 64 * p];

        // ---- kwta: top-6 of v, ties -> lowest index (matches lax.top_k) ----
        unsigned sel = 0;
        int xrs[6];
#pragma unroll
        for (int s = 0; s < K_IN; ++s) {
            double bv = -1e300;
            int bi = IN_F;
#pragma unroll
            for (int p = 0; p < 8; ++p) {
                if (sel & (1u << p)) continue;
                int i2 = lane + 64 * p;
                double vv = vd[p];
                if (vv > bv || (vv == bv && i2 < bi)) { bv = vv; bi = i2; }
            }
#pragma unroll
            for (int off = 32; off; off >>= 1) {
                double ov = __shfl_xor(bv, off);
                int oi = __shfl_xor(bi, off);
                if (ov > bv || (ov == bv && oi < bi)) { bv = ov; bi = oi; }
            }
            xrs[s] = bi;
            if (lane == (bi & 63)) sel |= 1u << (bi >> 6);
        }
        xr0 = xrs[0]; xr1 = xrs[1]; xr2 = xrs[2];
        xr3 = xrs[3]; xr4 = xrs[4]; xr5 = xrs[5];
    }

    // ---- outputs: encoded [rows][OUT_F], then xr [rows][IN_F] ----
    float* oenc = out + (size_t)row * OUT_F;
#pragma unroll
    for (int q = 0; q < 16; ++q) oenc[lane + 64 * q] = ((enc >> q) & 1u) ? 1.0f : 0.0f;

    float* oxr = out + (size_t)rows * OUT_F + (size_t)row * IN_F;
#pragma unroll
    for (int p = 0; p < 8; ++p) {
        int i = lane + 64 * p;
        float vo = (i == xr0 || i == xr1 || i == xr2 || i == xr3 || i == xr4 || i == xr5)
                       ? 1.0f : 0.0f;
        oxr[i] = vo;
    }
}

extern "C" void kernel_launch(void* const* d_in, const int* in_sizes, int n_in,
                              void* d_out, int out_size, void* d_ws, size_t ws_size,
                              hipStream_t stream) {
    const float* x = (const float*)d_in[0];
    const float* w = (const float*)d_in[1];
    float* out = (float*)d_out;
    const int rows = in_sizes[0] / IN_F;  // 4096

    const size_t wt_bytes = (size_t)IN_F * OUT_F * sizeof(float);
    const bool use_t = (ws_size >= wt_bytes) && (d_ws != nullptr);
    float* wT = (float*)d_ws;

    const int blocks = (rows + 3) / 4;
    if (use_t) {
        transpose_w_kernel<<<(IN_F * OUT_F + 255) / 256, 256, 0, stream>>>(w, wT);
        bmp_kernel<true><<<blocks, 256, 0, stream>>>(x, w, wT, out, rows);
    } else {
        bmp_kernel<false><<<blocks, 256, 0, stream>>>(x, w, nullptr, out, rows);
    }
}